// Round 13
// baseline (639.758 us; speedup 1.0000x reference)
//
#include <hip/hip_runtime.h>
#include <cstdint>
#include <cmath>

// Problem constants (from reference):
#define NN 50000
#define EE 500000
#define GG 2000
// IN=64, H=128, ED=16, OUT=1, NUM_GAT=2, T=2

#define DEV __device__ __forceinline__

typedef __attribute__((ext_vector_type(8))) short short8;
typedef __attribute__((ext_vector_type(4))) float floatx4;
typedef _Float16 half2v __attribute__((ext_vector_type(2)));
typedef _Float16 half4v __attribute__((ext_vector_type(4)));
typedef _Float16 half8v __attribute__((ext_vector_type(8)));

// fast overflow-safe sigmoid/tanh via hardware exp
DEV float fsig(float x) { return 1.f / (1.f + __expf(-x)); }
DEV float ftanh(float x) {
    const float e = __expf(-2.f * fabsf(x));   // in (0,1], never overflows
    const float t = (1.f - e) / (1.f + e);
    return x >= 0.f ? t : -t;
}

DEV float actf(float x, int act) {
    if (act == 1) return x >= 0.f ? x : 0.01f * x;          // leaky 0.01
    if (act == 2) return x > 0.f ? x : __expf(x) - 1.f;     // elu
    if (act == 3) return x > 0.f ? x : 0.f;                 // relu
    return x;
}

DEV float hdot2(half2v a, half2v b, float c) {
#if __has_builtin(__builtin_amdgcn_fdot2)
    return __builtin_amdgcn_fdot2(a, b, c, false);
#else
    return c + (float)a[0] * (float)b[0] + (float)a[1] * (float)b[1];
#endif
}

#define H2(v, i) __builtin_shufflevector(v, v, 2 * (i), 2 * (i) + 1)

// ---------------------------------------------------------------------------
// f16 MFMA GEMM: C[M,Nout] = act(A[M,K] @ W[Nout,K]^T + bias), f16 in/out,
// fp32 accum. K in {64,128}. Block 256/4 waves, 64x64 tile.
// ---------------------------------------------------------------------------
__global__ __launch_bounds__(256) void gemm_f16_k(
    const _Float16* __restrict__ A, const _Float16* __restrict__ W,
    const float* __restrict__ bias, _Float16* __restrict__ C,
    int M, int K, int Nout, int act)
{
    __shared__ unsigned short Als[64 * 136];
    __shared__ unsigned short Bls[64 * 136];
    const int tid = threadIdx.x;
    const int bm = blockIdx.y * 64;
    const int bn = blockIdx.x * 64;

    const int ks = (K == 128) ? 7 : 6;
    const int km = K - 1;
    const int nch = (64 * K) >> 3;          // 16B chunks
    for (int i = tid; i < nch; i += 256) {
        const int e8 = i << 3;
        const int r = e8 >> ks;
        const int c = e8 & km;
        short8 av = {};
        if (bm + r < M) av = *(const short8*)(A + (size_t)(bm + r) * K + c);
        *(short8*)(Als + r * 136 + c) = av;
        *(short8*)(Bls + r * 136 + c) = *(const short8*)(W + (size_t)(bn + r) * K + c);
    }
    __syncthreads();

    const int wave = tid >> 6;
    const int lane = tid & 63;
    const int wr = (wave >> 1) * 32;
    const int wc = (wave & 1) * 32;
    const int l15 = lane & 15;
    const int quad = lane >> 4;

    floatx4 acc00 = {}, acc01 = {}, acc10 = {}, acc11 = {};
    for (int k0 = 0; k0 < K; k0 += 32) {
        const half8v a0 = *(const half8v*)(Als + (wr + l15) * 136 + k0 + quad * 8);
        const half8v a1 = *(const half8v*)(Als + (wr + 16 + l15) * 136 + k0 + quad * 8);
        const half8v b0 = *(const half8v*)(Bls + (wc + l15) * 136 + k0 + quad * 8);
        const half8v b1 = *(const half8v*)(Bls + (wc + 16 + l15) * 136 + k0 + quad * 8);
        acc00 = __builtin_amdgcn_mfma_f32_16x16x32_f16(a0, b0, acc00, 0, 0, 0);
        acc01 = __builtin_amdgcn_mfma_f32_16x16x32_f16(a0, b1, acc01, 0, 0, 0);
        acc10 = __builtin_amdgcn_mfma_f32_16x16x32_f16(a1, b0, acc10, 0, 0, 0);
        acc11 = __builtin_amdgcn_mfma_f32_16x16x32_f16(a1, b1, acc11, 0, 0, 0);
    }

    const floatx4* accs[4] = { &acc00, &acc01, &acc10, &acc11 };
#pragma unroll
    for (int r = 0; r < 2; ++r) {
#pragma unroll
        for (int c = 0; c < 2; ++c) {
            const floatx4 a = *accs[r * 2 + c];
            const int n = bn + wc + c * 16 + l15;
            const float bv = bias ? bias[n] : 0.f;
#pragma unroll
            for (int i = 0; i < 4; ++i) {
                const int m = bm + wr + r * 16 + quad * 4 + i;
                if (m < M) C[(size_t)m * Nout + n] = (_Float16)actf(a[i] + bv, act);
            }
        }
    }
}

// ---------------------------------------------------------------------------
// GAT xp GEMM with fused attention dots: C = A @ W^T (f16), plus per-row
// partial dots ssrc[m] += sum_n C[m,n]*asrc[n], sdst likewise (fp32 accs,
// shfl-reduced over the 16-lane col group, one atomicAdd per row per wave).
// K = Nout = 128. Replaces gemm + node_dots.
// ---------------------------------------------------------------------------
__global__ __launch_bounds__(256) void gemm_dots_k(
    const _Float16* __restrict__ A, const _Float16* __restrict__ W,
    _Float16* __restrict__ C, const float* __restrict__ asrc,
    const float* __restrict__ adst, float* __restrict__ ssrc,
    float* __restrict__ sdst, int M)
{
    __shared__ unsigned short Als[64 * 136];
    __shared__ unsigned short Bls[64 * 136];
    const int tid = threadIdx.x;
    const int bm = blockIdx.y * 64;
    const int bn = blockIdx.x * 64;

    for (int i = tid; i < 1024; i += 256) {
        const int e8 = i << 3;
        const int r = e8 >> 7;
        const int c = e8 & 127;
        short8 av = {};
        if (bm + r < M) av = *(const short8*)(A + (size_t)(bm + r) * 128 + c);
        *(short8*)(Als + r * 136 + c) = av;
        *(short8*)(Bls + r * 136 + c) = *(const short8*)(W + (size_t)(bn + r) * 128 + c);
    }
    __syncthreads();

    const int wave = tid >> 6;
    const int lane = tid & 63;
    const int wr = (wave >> 1) * 32;
    const int wc = (wave & 1) * 32;
    const int l15 = lane & 15;
    const int quad = lane >> 4;

    floatx4 acc00 = {}, acc01 = {}, acc10 = {}, acc11 = {};
    for (int k0 = 0; k0 < 128; k0 += 32) {
        const half8v a0 = *(const half8v*)(Als + (wr + l15) * 136 + k0 + quad * 8);
        const half8v a1 = *(const half8v*)(Als + (wr + 16 + l15) * 136 + k0 + quad * 8);
        const half8v b0 = *(const half8v*)(Bls + (wc + l15) * 136 + k0 + quad * 8);
        const half8v b1 = *(const half8v*)(Bls + (wc + 16 + l15) * 136 + k0 + quad * 8);
        acc00 = __builtin_amdgcn_mfma_f32_16x16x32_f16(a0, b0, acc00, 0, 0, 0);
        acc01 = __builtin_amdgcn_mfma_f32_16x16x32_f16(a0, b1, acc01, 0, 0, 0);
        acc10 = __builtin_amdgcn_mfma_f32_16x16x32_f16(a1, b0, acc10, 0, 0, 0);
        acc11 = __builtin_amdgcn_mfma_f32_16x16x32_f16(a1, b1, acc11, 0, 0, 0);
    }

    // write C
    const floatx4* accs[4] = { &acc00, &acc01, &acc10, &acc11 };
#pragma unroll
    for (int r = 0; r < 2; ++r)
#pragma unroll
        for (int c = 0; c < 2; ++c) {
            const floatx4 a = *accs[r * 2 + c];
            const int n = bn + wc + c * 16 + l15;
#pragma unroll
            for (int i = 0; i < 4; ++i) {
                const int m = bm + wr + r * 16 + quad * 4 + i;
                if (m < M) C[(size_t)m * 128 + n] = (_Float16)a[i];
            }
        }

    // fused dots
    const int n0 = bn + wc + l15;
    const int n1 = n0 + 16;
    const float as0 = asrc[n0], as1 = asrc[n1];
    const float ad0 = adst[n0], ad1 = adst[n1];
#pragma unroll
    for (int r = 0; r < 2; ++r) {
        const floatx4 a0 = r ? acc10 : acc00;
        const floatx4 a1 = r ? acc11 : acc01;
#pragma unroll
        for (int i = 0; i < 4; ++i) {
            float vs = a0[i] * as0 + a1[i] * as1;
            float vd = a0[i] * ad0 + a1[i] * ad1;
            vs += __shfl_down(vs, 8, 16);
            vs += __shfl_down(vs, 4, 16);
            vs += __shfl_down(vs, 2, 16);
            vs += __shfl_down(vs, 1, 16);
            vd += __shfl_down(vd, 8, 16);
            vd += __shfl_down(vd, 4, 16);
            vd += __shfl_down(vd, 2, 16);
            vd += __shfl_down(vd, 1, 16);
            const int m = bm + wr + r * 16 + quad * 4 + i;
            if (l15 == 0 && m < M) {
                atomicAdd(ssrc + m, vs);
                atomicAdd(sdst + m, vd);
            }
        }
    }
}

// ---------------------------------------------------------------------------
// Fused lin1 + p GEMM: x1 = leaky(x @ lin1_w^T + b) (written to global AND
// kept in LDS), then p = x1 @ nd1wA^T. Block = 64 rows x 128 cols, 4 waves
// in 2x2 (32 rows x 64 cols each); weights read from global (L2-hot).
// ---------------------------------------------------------------------------
__global__ __launch_bounds__(256) void lin1p_k(
    const _Float16* __restrict__ xH, const _Float16* __restrict__ lin1_wH,
    const float* __restrict__ lin1_b, const _Float16* __restrict__ nd1wAH,
    _Float16* __restrict__ x1H, _Float16* __restrict__ pH, int M)
{
    __shared__ _Float16 sXin[64 * 72];
    __shared__ _Float16 sX1 [64 * 136];
    const int tid = threadIdx.x;
    const int bm = blockIdx.x * 64;

    // stage x tile (64 x 64 f16)
    for (int i = tid; i < 512; i += 256) {
        const int e8 = i << 3;
        const int r = e8 >> 6;
        const int c = e8 & 63;
        const int m = bm + r;
        half8v v = {};
        if (m < M) v = *(const half8v*)(xH + (size_t)m * 64 + c);
        *(half8v*)(sXin + r * 72 + c) = v;
    }
    __syncthreads();

    const int wave = tid >> 6, lane = tid & 63;
    const int l15 = lane & 15, quad = lane >> 4;
    const int wr = (wave >> 1) * 32;
    const int wc = (wave & 1) * 64;

    // stage 1: x1 = leaky(x @ lin1_w^T + b), K=64
    {
        floatx4 acc[2][4] = {};
#pragma unroll
        for (int k = 0; k < 2; ++k) {
            half8v a[2];
#pragma unroll
            for (int rf = 0; rf < 2; ++rf)
                a[rf] = *(const half8v*)(sXin + (wr + rf * 16 + l15) * 72 + k * 32 + quad * 8);
#pragma unroll
            for (int ct = 0; ct < 4; ++ct) {
                const half8v b = *(const half8v*)(lin1_wH + (size_t)(wc + ct * 16 + l15) * 64 + k * 32 + quad * 8);
#pragma unroll
                for (int rf = 0; rf < 2; ++rf)
                    acc[rf][ct] = __builtin_amdgcn_mfma_f32_16x16x32_f16(a[rf], b, acc[rf][ct], 0, 0, 0);
            }
        }
#pragma unroll
        for (int rf = 0; rf < 2; ++rf)
#pragma unroll
            for (int ct = 0; ct < 4; ++ct) {
                const int n = wc + ct * 16 + l15;
                const float bv = lin1_b[n];
#pragma unroll
                for (int i = 0; i < 4; ++i) {
                    const int rloc = wr + rf * 16 + quad * 4 + i;
                    float v = acc[rf][ct][i] + bv;
                    v = v >= 0.f ? v : 0.01f * v;
                    const _Float16 h = (_Float16)v;
                    sX1[rloc * 136 + n] = h;
                    const int m = bm + rloc;
                    if (m < M) x1H[(size_t)m * 128 + n] = h;
                }
            }
    }
    __syncthreads();

    // stage 2: p = x1 @ nd1wA^T, K=128
    {
        floatx4 acc[2][4] = {};
#pragma unroll
        for (int k = 0; k < 4; ++k) {
            half8v a[2];
#pragma unroll
            for (int rf = 0; rf < 2; ++rf)
                a[rf] = *(const half8v*)(sX1 + (wr + rf * 16 + l15) * 136 + k * 32 + quad * 8);
#pragma unroll
            for (int ct = 0; ct < 4; ++ct) {
                const half8v b = *(const half8v*)(nd1wAH + (size_t)(wc + ct * 16 + l15) * 128 + k * 32 + quad * 8);
#pragma unroll
                for (int rf = 0; rf < 2; ++rf)
                    acc[rf][ct] = __builtin_amdgcn_mfma_f32_16x16x32_f16(a[rf], b, acc[rf][ct], 0, 0, 0);
            }
        }
#pragma unroll
        for (int rf = 0; rf < 2; ++rf)
#pragma unroll
            for (int ct = 0; ct < 4; ++ct) {
                const int n = wc + ct * 16 + l15;
#pragma unroll
                for (int i = 0; i < 4; ++i) {
                    const int m = bm + wr + rf * 16 + quad * 4 + i;
                    if (m < M) pH[(size_t)m * 128 + n] = (_Float16)acc[rf][ct][i];
                }
            }
    }
}

// ---------------------------------------------------------------------------
// Fused GRU v6 (f16): block = 64 rows x 64 cols, grid.y=2 col-halves.
// rz-fused accumulators, k-outer loop, VGPR<=128 (4 waves/SIMD), fast exp.
// ---------------------------------------------------------------------------
__global__ __launch_bounds__(256, 4) void gru_fused4_k(
    const _Float16* __restrict__ xin, const _Float16* __restrict__ hin,
    const _Float16* __restrict__ wih, const _Float16* __restrict__ whh,
    const float* __restrict__ bih, const float* __restrict__ bhh,
    _Float16* __restrict__ xout, int M)
{
    __shared__ unsigned short sX[64 * 136];
    __shared__ unsigned short sH[64 * 136];

    const int tid = threadIdx.x;
    const int bm = blockIdx.x * 64;

    for (int i = tid; i < 1024; i += 256) {
        const int e8 = i << 3;
        const int r = e8 >> 7;
        const int c = e8 & 127;
        const int m = bm + r;
        short8 xv = {}, hv = {};
        if (m < M) {
            xv = *(const short8*)(xin + (size_t)m * 128 + c);
            hv = *(const short8*)(hin + (size_t)m * 128 + c);
        }
        *(short8*)(sX + r * 136 + c) = xv;
        *(short8*)(sH + r * 136 + c) = hv;
    }
    __syncthreads();

    const int wave = tid >> 6;
    const int lane = tid & 63;
    const int l15 = lane & 15;
    const int quad = lane >> 4;
    const int j0 = (blockIdx.y * 4 + wave) * 16;
    const int j = j0 + l15;

    const float br  = bih[j] + bhh[j];
    const float bz  = bih[128 + j] + bhh[128 + j];
    const float bni = bih[256 + j];
    const float bnh = bhh[256 + j];

    floatx4 aR[4] = {}, aZ[4] = {}, aNi[4] = {}, aNh[4] = {};

#pragma unroll
    for (int k = 0; k < 4; ++k) {
        const size_t wrow = (size_t)(j0 + l15) * 128 + k * 32 + quad * 8;
        const half8v wri = *(const half8v*)(wih + wrow);
        const half8v wzi = *(const half8v*)(wih + 128 * 128 + wrow);
        const half8v wni = *(const half8v*)(wih + 2 * 128 * 128 + wrow);
        const half8v wrh = *(const half8v*)(whh + wrow);
        const half8v wzh = *(const half8v*)(whh + 128 * 128 + wrow);
        const half8v wnh = *(const half8v*)(whh + 2 * 128 * 128 + wrow);
#pragma unroll
        for (int rf = 0; rf < 4; ++rf) {
            const half8v ax = *(const half8v*)(sX + (rf * 16 + l15) * 136 + k * 32 + quad * 8);
            const half8v ah = *(const half8v*)(sH + (rf * 16 + l15) * 136 + k * 32 + quad * 8);
            aR[rf]  = __builtin_amdgcn_mfma_f32_16x16x32_f16(ax, wri, aR[rf], 0, 0, 0);
            aR[rf]  = __builtin_amdgcn_mfma_f32_16x16x32_f16(ah, wrh, aR[rf], 0, 0, 0);
            aZ[rf]  = __builtin_amdgcn_mfma_f32_16x16x32_f16(ax, wzi, aZ[rf], 0, 0, 0);
            aZ[rf]  = __builtin_amdgcn_mfma_f32_16x16x32_f16(ah, wzh, aZ[rf], 0, 0, 0);
            aNi[rf] = __builtin_amdgcn_mfma_f32_16x16x32_f16(ax, wni, aNi[rf], 0, 0, 0);
            aNh[rf] = __builtin_amdgcn_mfma_f32_16x16x32_f16(ah, wnh, aNh[rf], 0, 0, 0);
        }
    }

#pragma unroll
    for (int rf = 0; rf < 4; ++rf) {
#pragma unroll
        for (int i = 0; i < 4; ++i) {
            const int m = bm + rf * 16 + quad * 4 + i;
            if (m >= M) continue;
            const float rg = fsig(aR[rf][i] + br);
            const float zg = fsig(aZ[rf][i] + bz);
            const float ng = ftanh(aNi[rf][i] + bni + rg * (aNh[rf][i] + bnh));
            const float hp = (float)((const _Float16*)sH)[(rf * 16 + quad * 4 + i) * 136 + j];
            const float v = (1.f - zg) * ng + zg * hp;
            xout[(size_t)m * 128 + j] = (_Float16)(v > 0.f ? v : 0.f);
        }
    }
}

// ---------------------------------------------------------------------------
// CSR build: histogram + two-level scan + slot fill (stateless per launch).
// ---------------------------------------------------------------------------
__global__ void hist_k(const int* __restrict__ ei, int* __restrict__ deg, int E)
{
    int e = blockIdx.x * 256 + threadIdx.x;
    if (e >= E) return;
    atomicAdd(deg + ei[E + e], 1);
}

__global__ __launch_bounds__(1024) void scan_part_k(const int* __restrict__ deg,
                                                    int* __restrict__ bsum, int n)
{
    __shared__ int sh[1024];
    const int t = threadIdx.x;
    const int i = blockIdx.x * 1024 + t;
    sh[t] = (i < n) ? deg[i] : 0;
    __syncthreads();
#pragma unroll
    for (int off = 512; off; off >>= 1) {
        if (t < off) sh[t] += sh[t + off];
        __syncthreads();
    }
    if (t == 0) bsum[blockIdx.x] = sh[0];
}

__global__ void scan_tops_k(const int* __restrict__ bsum, int* __restrict__ boff,
                            int nb, int* __restrict__ rowptr, int n)
{
    if (threadIdx.x != 0 || blockIdx.x != 0) return;
    int run = 0;
    for (int b = 0; b < nb; ++b) { boff[b] = run; run += bsum[b]; }
    rowptr[n] = run;
}

__global__ __launch_bounds__(1024) void scan_final_k(const int* __restrict__ deg,
                                                     const int* __restrict__ boff,
                                                     int* __restrict__ rowptr, int n)
{
    __shared__ int sh[1024];
    const int t = threadIdx.x;
    const int i = blockIdx.x * 1024 + t;
    const int v = (i < n) ? deg[i] : 0;
    sh[t] = v;
    __syncthreads();
#pragma unroll
    for (int off = 1; off < 1024; off <<= 1) {
        int add = (t >= off) ? sh[t - off] : 0;
        __syncthreads();
        sh[t] += add;
        __syncthreads();
    }
    if (i < n) rowptr[i] = boff[blockIdx.x] + sh[t] - v;   // exclusive
}

__global__ void fill_csr_k(const int* __restrict__ ei, const int* __restrict__ rowptr,
                           int* __restrict__ cursor, int* __restrict__ csr_src,
                           int* __restrict__ csr_eid, int E)
{
    int e = blockIdx.x * 256 + threadIdx.x;
    if (e >= E) return;
    int s = ei[e], d = ei[E + e];
    int pos = atomicAdd(cursor + d, 1);
    int slot = rowptr[d] + pos;
    csr_src[slot] = s;
    csr_eid[slot] = e;
}

// batch is sorted: fill gptr[g] = first node of graph g (gptr[G] = N)
__global__ void gptr_k(const int* __restrict__ batch, int* __restrict__ gptr,
                       int N, int G)
{
    int n = blockIdx.x * 256 + threadIdx.x;
    if (n >= N) return;
    if (n == 0) {
        for (int g = 0; g <= batch[0]; ++g) gptr[g] = 0;
    } else {
        const int a = batch[n - 1], b = batch[n];
        for (int g = a + 1; g <= b; ++g) gptr[g] = n;
    }
    if (n == N - 1) {
        for (int g = batch[N - 1] + 1; g <= G; ++g) gptr[g] = N;
    }
}

// per-graph contiguous sum (no atomics, G-wide parallel): aggH f16
__global__ __launch_bounds__(128) void graph_sum_k(
    const _Float16* __restrict__ xc, const int* __restrict__ gptr,
    _Float16* __restrict__ aggH)
{
    const int g = blockIdx.x;
    const int t = threadIdx.x;   // feature
    const int n0 = gptr[g], n1 = gptr[g + 1];
    float acc = 0.f;
    for (int n = n0; n < n1; ++n) acc += (float)xc[(size_t)n * 128 + t];
    aggH[(size_t)g * 128 + t] = (_Float16)acc;
}

// ---------------------------------------------------------------------------
// Multi-segment fp32 -> f16 conversion (one dispatch for all flat tensors)
// ---------------------------------------------------------------------------
struct CvtSeg { const float* src; _Float16* dst; int n; };
struct CvtArgs { CvtSeg s[12]; int count; };

__global__ void cvt_multi_k(CvtArgs a)
{
    const int seg = blockIdx.y;
    if (seg >= a.count) return;
    const CvtSeg cs = a.s[seg];
    for (int i = blockIdx.x * 256 + threadIdx.x; i < cs.n; i += gridDim.x * 256)
        cs.dst[i] = (_Float16)cs.src[i];
}

// nd_lin1_w[:,0:128] (pitch 144) -> packed f16 [128][128]
__global__ void cvt_ndwA_k(const float* __restrict__ ndw, _Float16* __restrict__ outp)
{
    int t = blockIdx.x * 256 + threadIdx.x;
    if (t >= 16384) return;
    int r = t >> 7, c = t & 127;
    outp[r * 128 + c] = (_Float16)ndw[r * 144 + c];
}

// nd_lin1_w[:,128:144] (pitch 144) -> f16 table [128][16]
__global__ void cvt_ndwB_k(const float* __restrict__ ndw, _Float16* __restrict__ outp)
{
    int t = blockIdx.x * 256 + threadIdx.x;
    if (t >= 2048) return;
    int r = t >> 4, k = t & 15;
    outp[r * 16 + k] = (_Float16)ndw[r * 144 + 128 + k];
}

// ---------------------------------------------------------------------------
// nd_conv gather v4: 4 edge-groups x 32 feature-quads (4 edges in flight,
// mirrors gat_gather). out[d,h] = sum_e leaky(p[src,h] + ea[e].W1b[h]).
// ---------------------------------------------------------------------------
__global__ __launch_bounds__(128) void nd_gather_k(
    const int* __restrict__ rowptr, const int* __restrict__ csr_src,
    const int* __restrict__ csr_eid, const _Float16* __restrict__ eaH,
    const _Float16* __restrict__ wH, const _Float16* __restrict__ pH,
    _Float16* __restrict__ outp)
{
    __shared__ float racc[4][128];
    const int d = blockIdx.x;
    const int t = threadIdx.x;
    const int g  = t >> 5;       // edge group 0..3
    const int fq = t & 31;       // features 4fq..4fq+3

    // weights for this thread's 4 features (4 x 16 f16 = 32 VGPR)
    half8v w0[4], w1[4];
#pragma unroll
    for (int f = 0; f < 4; ++f) {
        w0[f] = *(const half8v*)(wH + (fq * 4 + f) * 16);
        w1[f] = *(const half8v*)(wH + (fq * 4 + f) * 16 + 8);
    }

    const int b0 = rowptr[d], b1 = rowptr[d + 1];
    float acc[4] = {};
    for (int i = b0 + g; i < b1; i += 4) {
        const int s = csr_src[i], e = csr_eid[i];
        const half8v e0 = *(const half8v*)(eaH + (size_t)e * 16);
        const half8v e1 = *(const half8v*)(eaH + (size_t)e * 16 + 8);
        const half4v p4 = *(const half4v*)(pH + (size_t)s * 128 + fq * 4);
#pragma unroll
        for (int f = 0; f < 4; ++f) {
            float q = 0.f;
            q = hdot2(H2(e0, 0), H2(w0[f], 0), q);
            q = hdot2(H2(e0, 1), H2(w0[f], 1), q);
            q = hdot2(H2(e0, 2), H2(w0[f], 2), q);
            q = hdot2(H2(e0, 3), H2(w0[f], 3), q);
            q = hdot2(H2(e1, 0), H2(w1[f], 0), q);
            q = hdot2(H2(e1, 1), H2(w1[f], 1), q);
            q = hdot2(H2(e1, 2), H2(w1[f], 2), q);
            q = hdot2(H2(e1, 3), H2(w1[f], 3), q);
            const float v = (float)p4[f] + q;
            acc[f] += v >= 0.f ? v : 0.01f * v;
        }
    }
#pragma unroll
    for (int f = 0; f < 4; ++f) racc[g][fq * 4 + f] = acc[f];
    __syncthreads();

    outp[(size_t)d * 128 + t] =
        (_Float16)(racc[0][t] + racc[1][t] + racc[2][t] + racc[3][t]);
}

// ---------------------------------------------------------------------------
// Fused GAT aggregation -- one pass (softmax shift-invariance, |a| small)
// ---------------------------------------------------------------------------
__global__ __launch_bounds__(128) void gat_gather_k(
    const int* __restrict__ rowptr, const int* __restrict__ csr_src,
    const float* __restrict__ ssrc, const float* __restrict__ sdst,
    const _Float16* __restrict__ xp, const float* __restrict__ bias,
    _Float16* __restrict__ outp)
{
    const int d = blockIdx.x;
    const int t = threadIdx.x;
    __shared__ float red[128];
    __shared__ float lw[128];
    __shared__ int   ls[128];
    __shared__ float racc[4][128];

    const int b0 = rowptr[d], b1 = rowptr[d + 1];
    const int deg = b1 - b0;
    const float sdd = sdst[d];

    const int g  = t >> 5;       // edge group 0..3
    const int fq = t & 31;       // feature quad
    float4 acc = make_float4(0.f, 0.f, 0.f, 0.f);
    float dpart = 0.f;
    for (int base = b0; base < b1; base += 128) {
        const int len = min(128, b1 - base);
        if (t < len) {
            const int s = csr_src[base + t];
            float a = ssrc[s] + sdd;
            a = a >= 0.f ? a : 0.01f * a;
            const float w = __expf(a);     // |a| small -> safe
            lw[t] = w;
            ls[t] = s;
            dpart += w;
        }
        __syncthreads();
        for (int j = 0; j < len; j += 4) {
            const int jj = j + g;
            if (jj < len) {
                const float w = lw[jj];
                const half4v hv = *(const half4v*)(xp + (size_t)ls[jj] * 128 + fq * 4);
                acc.x += w * (float)hv[0];
                acc.y += w * (float)hv[1];
                acc.z += w * (float)hv[2];
                acc.w += w * (float)hv[3];
            }
        }
        __syncthreads();
    }

    red[t] = dpart;
    __syncthreads();
#pragma unroll
    for (int off = 64; off; off >>= 1) {
        if (t < off) red[t] += red[t + off];
        __syncthreads();
    }
    const float denom = red[0];

    racc[g][fq * 4 + 0] = acc.x;
    racc[g][fq * 4 + 1] = acc.y;
    racc[g][fq * 4 + 2] = acc.z;
    racc[g][fq * 4 + 3] = acc.w;
    __syncthreads();

    const float s4 = racc[0][t] + racc[1][t] + racc[2][t] + racc[3][t];
    float v = (deg > 0 ? s4 / denom : 0.f) + bias[t];
    outp[(size_t)d * 128 + t] = (_Float16)(v > 0.f ? v : __expf(v) - 1.f);   // elu
}

// ---------------------------------------------------------------------------
// Fused GIN+LSTM readout: 16 graphs/block (125 blocks, 25.6 KB LDS).
// ---------------------------------------------------------------------------
__global__ __launch_bounds__(256) void gin_lstm_k(
    const _Float16* __restrict__ aggH,
    const _Float16* __restrict__ ginw, const float* __restrict__ ginb,
    const _Float16* __restrict__ lwih, const _Float16* __restrict__ lwhh,
    const float* __restrict__ lbih, const float* __restrict__ lbhh,
    const float* __restrict__ l2w, const float* __restrict__ l2b,
    float* __restrict__ y, int G)
{
    __shared__ _Float16 sOa[16 * 136];
    __shared__ _Float16 sOb[16 * 136];
    __shared__ _Float16 sG [16 * 136];
    __shared__ _Float16 sT [16 * 136];   // hg (f16, GEMM operand)
    __shared__ float    sC [16 * 128];   // hg (fp32, cell state)

    const int tid = threadIdx.x, wave = tid >> 6, lane = tid & 63;
    const int l15 = lane & 15, quad = lane >> 4;
    const int g0 = blockIdx.x * 16;

    {
        const int r = tid >> 4;           // 0..15
        const int c = (tid & 15) * 8;
        half8v v = {};
        if (g0 + r < G) v = *(const half8v*)(aggH + (size_t)(g0 + r) * 128 + c);
        *(half8v*)(sG + r * 136 + c) = v;
        half8v rv;
#pragma unroll
        for (int i = 0; i < 8; ++i) rv[i] = (float)v[i] > 0.f ? v[i] : (_Float16)0.f;
        *(half8v*)(sOa + r * 136 + c) = rv;
    }
    __syncthreads();

    _Float16* sIn = sOa;
    _Float16* sOut = sOb;
#pragma unroll
    for (int ts = 0; ts < 2; ++ts) {
        for (int ci = 0; ci < 2; ++ci) {
            const int j0 = (wave * 2 + ci) * 16;
            floatx4 acc = {};
#pragma unroll
            for (int k = 0; k < 4; ++k) {
                const half8v b = *(const half8v*)(ginw + (size_t)(j0 + l15) * 128 + k * 32 + quad * 8);
                const half8v a = *(const half8v*)(sIn + l15 * 136 + k * 32 + quad * 8)
                               + *(const half8v*)(sG  + l15 * 136 + k * 32 + quad * 8);
                acc = __builtin_amdgcn_mfma_f32_16x16x32_f16(a, b, acc, 0, 0, 0);
            }
            const int j = j0 + l15;
            const float bg = ginb[j];
#pragma unroll
            for (int i = 0; i < 4; ++i) {
                const int row = quad * 4 + i;
                float v = acc[i] + bg;
                v = v > 0.f ? v : __expf(v) - 1.f;
                sT[row * 136 + j] = (_Float16)v;
                sC[row * 128 + j] = v;
            }
        }
        __syncthreads();

        for (int ci = 0; ci < 2; ++ci) {
            const int j0 = (wave * 2 + ci) * 16;
            floatx4 acc[4] = {};
#pragma unroll
            for (int k = 0; k < 4; ++k) {
                const half8v ao = *(const half8v*)(sIn + l15 * 136 + k * 32 + quad * 8);
                const half8v ah = *(const half8v*)(sT  + l15 * 136 + k * 32 + quad * 8);
#pragma unroll
                for (int gt = 0; gt < 4; ++gt) {
                    const half8v bw = *(const half8v*)(lwih + (size_t)(gt * 128 + j0 + l15) * 128 + k * 32 + quad * 8);
                    const half8v bh = *(const half8v*)(lwhh + (size_t)(gt * 128 + j0 + l15) * 128 + k * 32 + quad * 8);
                    acc[gt] = __builtin_amdgcn_mfma_f32_16x16x32_f16(ao, bw, acc[gt], 0, 0, 0);
                    acc[gt] = __builtin_amdgcn_mfma_f32_16x16x32_f16(ah, bh, acc[gt], 0, 0, 0);
                }
            }
            const int j = j0 + l15;
            const float bi_ = lbih[j]       + lbhh[j];
            const float bf_ = lbih[128 + j] + lbhh[128 + j];
            const float bgg = lbih[256 + j] + lbhh[256 + j];
            const float bo_ = lbih[384 + j] + lbhh[384 + j];
#pragma unroll
            for (int i = 0; i < 4; ++i) {
                const int row = quad * 4 + i;
                const float hg = sC[row * 128 + j];
                const float c2 = fsig(acc[1][i] + bf_) * hg
                               + fsig(acc[0][i] + bi_) * ftanh(acc[2][i] + bgg);
                const float on = fsig(acc[3][i] + bo_) * ftanh(c2);
                sOut[row * 136 + j] = (_Float16)on;
            }
        }
        __syncthreads();
        _Float16* tmp = sIn; sIn = sOut; sOut = tmp;
    }

    if (tid < 64) {
        const int r = tid >> 2;      // 0..15
        const int part = tid & 3;
        float v = 0.f;
        for (int j = part * 32; j < part * 32 + 32; ++j)
            v += (float)sIn[r * 136 + j] * l2w[j];
        v += __shfl_down(v, 2);
        v += __shfl_down(v, 1);
        if (part == 0 && g0 + r < G) y[g0 + r] = v + l2b[0];
    }
}

// ---------------------------------------------------------------------------

extern "C" void kernel_launch(void* const* d_in, const int* in_sizes, int n_in,
                              void* d_out, int out_size, void* d_ws, size_t ws_size,
                              hipStream_t stream)
{
    const float* x      = (const float*)d_in[0];
    const int*   ei     = (const int*)  d_in[1];
    const float* ea     = (const float*)d_in[2];
    const int*   batch  = (const int*)  d_in[3];
    const float* lin1_w = (const float*)d_in[4];
    const float* lin1_b = (const float*)d_in[5];
    const float* nd1w   = (const float*)d_in[6];
    const float* nd2w   = (const float*)d_in[7];
    const float* ndb    = (const float*)d_in[8];
    const float* g0wih  = (const float*)d_in[9];
    const float* g0whh  = (const float*)d_in[10];
    const float* g0bih  = (const float*)d_in[11];
    const float* g0bhh  = (const float*)d_in[12];
    const float* gatw   = (const float*)d_in[13];
    const float* gatas  = (const float*)d_in[14];
    const float* gatad  = (const float*)d_in[15];
    const float* gatb   = (const float*)d_in[16];
    const float* gwih   = (const float*)d_in[17];
    const float* gwhh   = (const float*)d_in[18];
    const float* gbih   = (const float*)d_in[19];
    const float* gbhh   = (const float*)d_in[20];
    const float* ginw   = (const float*)d_in[21];
    const float* ginb   = (const float*)d_in[22];
    const float* lwih   = (const float*)d_in[23];
    const float* lwhh   = (const float*)d_in[24];
    const float* lbih   = (const float*)d_in[25];
    const float* lbhh   = (const float*)d_in[26];
    const float* l2w    = (const float*)d_in[27];
    const float* l2b    = (const float*)d_in[28];
    float* outp = (float*)d_out;

    const int N = NN, E = EE, G = GG;
    const int Npad = (N + 63) & ~63;

    float* ws = (float*)d_ws;
    size_t off = 0;
    auto alloc = [&](size_t n) {
        float* r = ws + off;
        off += (n + 63) & ~(size_t)63;
        return r;
    };
    // f16 node pipeline (sizes in floats = halves/2)
    _Float16* xH    = (_Float16*)alloc((size_t)N * 32);   // N*64
    _Float16* x1H   = (_Float16*)alloc((size_t)N * 64);   // N*128 (ping)
    _Float16* hbufH = (_Float16*)alloc((size_t)N * 64);
    _Float16* accbH = (_Float16*)alloc((size_t)N * 64);
    _Float16* xcH   = (_Float16*)alloc((size_t)N * 64);   // (pong)
    _Float16* pH    = (_Float16*)alloc((size_t)N * 64);
    _Float16* eaH   = (_Float16*)alloc((size_t)E * 8);    // E*16
    _Float16* aggH  = (_Float16*)alloc((size_t)G * 64);   // G*128
    // f16 weights
    _Float16* lin1_wH = (_Float16*)alloc(4096);           // 128x64
    _Float16* nd1wAH  = (_Float16*)alloc(8192);           // 128x128
    _Float16* ndwBH   = (_Float16*)alloc(1024);           // 128x16
    _Float16* nd2wH   = (_Float16*)alloc(8192);
    _Float16* g0wihH  = (_Float16*)alloc(24576);
    _Float16* g0whhH  = (_Float16*)alloc(24576);
    _Float16* gwihH   = (_Float16*)alloc(49152);          // 2 layers
    _Float16* gwhhH   = (_Float16*)alloc(49152);
    _Float16* gatwH   = (_Float16*)alloc(16384);          // 2 layers
    _Float16* ginwH   = (_Float16*)alloc(8192);           // 128x128
    _Float16* lwihH   = (_Float16*)alloc(32768);          // 512x128
    _Float16* lwhhH   = (_Float16*)alloc(32768);
    // fp32 dot buffers (2 GAT layers, contiguous for single memset)
    float* ssrcA = alloc((size_t)N);
    float* sdstA = alloc((size_t)N);
    float* ssrcB = alloc((size_t)N);
    float* sdstB = alloc((size_t)N);
    // CSR + graph ptr
    int* deg     = (int*)alloc((size_t)N);
    int* rowptr  = (int*)alloc((size_t)N + 1);
    int* cursor  = (int*)alloc((size_t)N);
    int* bsum    = (int*)alloc(64);
    int* boff    = (int*)alloc(64);
    int* csr_src = (int*)alloc((size_t)E);
    int* csr_eid = (int*)alloc((size_t)E);
    int* gptr    = (int*)alloc((size_t)G + 1);
    (void)ws_size;

    auto gemmh = [&](const _Float16* A, const _Float16* W, const float* bias,
                     _Float16* C, int M, int K, int Nout, int act) {
        dim3 grid(Nout / 64, (M + 63) / 64);
        gemm_f16_k<<<grid, 256, 0, stream>>>(A, W, bias, C, M, K, Nout, act);
    };
    auto nb = [](int n) { return (n + 255) / 256; };

    auto gru = [&](const _Float16* xin, const _Float16* hin,
                   const _Float16* wih, const _Float16* whh,
                   const float* bih, const float* bhh, _Float16* xout) {
        dim3 grid((N + 63) / 64, 2);
        gru_fused4_k<<<grid, 256, 0, stream>>>(
            xin, hin, wih, whh, bih, bhh, xout, N);
    };

    // 0) CSR build + gptr + dot-buffer zero + all f16 conversions
    hipMemsetAsync(deg, 0, (size_t)N * 4, stream);
    hipMemsetAsync(cursor, 0, (size_t)N * 4, stream);
    hipMemsetAsync(ssrcA, 0, (size_t)Npad * 4 * 4, stream);   // ssrcA..sdstB
    hist_k<<<nb(E), 256, 0, stream>>>(ei, deg, E);
    const int nblk = (N + 1023) / 1024;   // 49
    scan_part_k<<<nblk, 1024, 0, stream>>>(deg, bsum, N);
    scan_tops_k<<<1, 64, 0, stream>>>(bsum, boff, nblk, rowptr, N);
    scan_final_k<<<nblk, 1024, 0, stream>>>(deg, boff, rowptr, N);
    fill_csr_k<<<nb(E), 256, 0, stream>>>(ei, rowptr, cursor, csr_src, csr_eid, E);
    gptr_k<<<nb(N), 256, 0, stream>>>(batch, gptr, N, G);

    CvtArgs ca;
    ca.s[0]  = { ea,     eaH,     E * 16 };
    ca.s[1]  = { x,      xH,      N * 64 };
    ca.s[2]  = { lin1_w, lin1_wH, 8192 };
    ca.s[3]  = { nd2w,   nd2wH,   16384 };
    ca.s[4]  = { g0wih,  g0wihH,  49152 };
    ca.s[5]  = { g0whh,  g0whhH,  49152 };
    ca.s[6]  = { gwih,   gwihH,   98304 };
    ca.s[7]  = { gwhh,   gwhhH,   98304 };
    ca.s[8]  = { gatw,   gatwH,   32768 };
    ca.s[9]  = { ginw,   ginwH,   16384 };
    ca.s[10] = { lwih,   lwihH,   65536 };
    ca.s[11] = { lwhh,   lwhhH,   65536 };
    ca.count = 12;
    cvt_multi_k<<<dim3(2048, 12), 256, 0, stream>>>(ca);
    cvt_ndwA_k<<<64, 256, 0, stream>>>(nd1w, nd1wAH);
    cvt_ndwB_k<<<8, 256, 0, stream>>>(nd1w, ndwBH);

    // 1+2a) fused: x1 = leaky(x @ lin1^T + b); p = x1 @ W1a^T
    lin1p_k<<<(N + 63) / 64, 256, 0, stream>>>(
        xH, lin1_wH, lin1_b, nd1wAH, x1H, pH, N);

    // 2b) nd gather + h GEMM
    nd_gather_k<<<N, 128, 0, stream>>>(rowptr, csr_src, csr_eid, eaH, ndwBH, pH, accbH);
    gemmh(accbH, nd2wH, ndb, hbufH, N, 128, 128, 2);

    // 3) xcur = relu(gru_cell(h, x1))
    gru(hbufH, x1H, g0wihH, g0whhH, g0bih, g0bhh, xcH);

    // 4) GAT layers (xp GEMM with fused attention dots)
    const _Float16* xcur = xcH;
    _Float16* xnext = x1H;
    for (int l = 0; l < 2; ++l) {
        float* ss = l ? ssrcB : ssrcA;
        float* sd = l ? sdstB : sdstA;
        dim3 grid(2, (N + 63) / 64);
        gemm_dots_k<<<grid, 256, 0, stream>>>(
            xcur, gatwH + (size_t)l * 16384, pH,
            gatas + l * 128, gatad + l * 128, ss, sd, N);
        gat_gather_k<<<N, 128, 0, stream>>>(rowptr, csr_src, ss, sd, pH,
                                            gatb + l * 128, hbufH);
        gru(hbufH, xcur, gwihH + (size_t)l * 49152, gwhhH + (size_t)l * 49152,
            gbih + l * 384, gbhh + l * 384, xnext);
        const _Float16* t = xcur; xcur = xnext; xnext = (_Float16*)t;
    }

    // 5) segment-sum (G-wide parallel)
    graph_sum_k<<<G, 128, 0, stream>>>(xcur, gptr, aggH);

    // 6-7) fused GIN+LSTM+final (16 graphs/block, 125 blocks)
    gin_lstm_k<<<(G + 15) / 16, 256, 0, stream>>>(
        aggH, ginwH, ginb, lwihH, lwhhH, lbih, lbhh, l2w, l2b, outp, G);
}

// Round 14
// 596.194 us; speedup vs baseline: 1.0731x; 1.0731x over previous
//
#include <hip/hip_runtime.h>
#include <cstdint>
#include <cmath>

// Problem constants (from reference):
#define NN 50000
#define EE 500000
#define GG 2000
// IN=64, H=128, ED=16, OUT=1, NUM_GAT=2, T=2

#define DEV __device__ __forceinline__

typedef __attribute__((ext_vector_type(8))) short short8;
typedef __attribute__((ext_vector_type(4))) float floatx4;
typedef _Float16 half2v __attribute__((ext_vector_type(2)));
typedef _Float16 half4v __attribute__((ext_vector_type(4)));
typedef _Float16 half8v __attribute__((ext_vector_type(8)));

// fast overflow-safe sigmoid/tanh via hardware exp
DEV float fsig(float x) { return 1.f / (1.f + __expf(-x)); }
DEV float ftanh(float x) {
    const float e = __expf(-2.f * fabsf(x));   // in (0,1], never overflows
    const float t = (1.f - e) / (1.f + e);
    return x >= 0.f ? t : -t;
}

DEV float actf(float x, int act) {
    if (act == 1) return x >= 0.f ? x : 0.01f * x;          // leaky 0.01
    if (act == 2) return x > 0.f ? x : __expf(x) - 1.f;     // elu
    if (act == 3) return x > 0.f ? x : 0.f;                 // relu
    return x;
}

DEV float hdot2(half2v a, half2v b, float c) {
#if __has_builtin(__builtin_amdgcn_fdot2)
    return __builtin_amdgcn_fdot2(a, b, c, false);
#else
    return c + (float)a[0] * (float)b[0] + (float)a[1] * (float)b[1];
#endif
}

#define H2(v, i) __builtin_shufflevector(v, v, 2 * (i), 2 * (i) + 1)

// ---------------------------------------------------------------------------
// f16 MFMA GEMM: C[M,Nout] = act(A[M,K] @ W[Nout,K]^T + bias), f16 in/out,
// fp32 accum. K in {64,128}. Block 256/4 waves, 64x64 tile.
// ---------------------------------------------------------------------------
__global__ __launch_bounds__(256) void gemm_f16_k(
    const _Float16* __restrict__ A, const _Float16* __restrict__ W,
    const float* __restrict__ bias, _Float16* __restrict__ C,
    int M, int K, int Nout, int act)
{
    __shared__ unsigned short Als[64 * 136];
    __shared__ unsigned short Bls[64 * 136];
    const int tid = threadIdx.x;
    const int bm = blockIdx.y * 64;
    const int bn = blockIdx.x * 64;

    const int ks = (K == 128) ? 7 : 6;
    const int km = K - 1;
    const int nch = (64 * K) >> 3;          // 16B chunks
    for (int i = tid; i < nch; i += 256) {
        const int e8 = i << 3;
        const int r = e8 >> ks;
        const int c = e8 & km;
        short8 av = {};
        if (bm + r < M) av = *(const short8*)(A + (size_t)(bm + r) * K + c);
        *(short8*)(Als + r * 136 + c) = av;
        *(short8*)(Bls + r * 136 + c) = *(const short8*)(W + (size_t)(bn + r) * K + c);
    }
    __syncthreads();

    const int wave = tid >> 6;
    const int lane = tid & 63;
    const int wr = (wave >> 1) * 32;
    const int wc = (wave & 1) * 32;
    const int l15 = lane & 15;
    const int quad = lane >> 4;

    floatx4 acc00 = {}, acc01 = {}, acc10 = {}, acc11 = {};
    for (int k0 = 0; k0 < K; k0 += 32) {
        const half8v a0 = *(const half8v*)(Als + (wr + l15) * 136 + k0 + quad * 8);
        const half8v a1 = *(const half8v*)(Als + (wr + 16 + l15) * 136 + k0 + quad * 8);
        const half8v b0 = *(const half8v*)(Bls + (wc + l15) * 136 + k0 + quad * 8);
        const half8v b1 = *(const half8v*)(Bls + (wc + 16 + l15) * 136 + k0 + quad * 8);
        acc00 = __builtin_amdgcn_mfma_f32_16x16x32_f16(a0, b0, acc00, 0, 0, 0);
        acc01 = __builtin_amdgcn_mfma_f32_16x16x32_f16(a0, b1, acc01, 0, 0, 0);
        acc10 = __builtin_amdgcn_mfma_f32_16x16x32_f16(a1, b0, acc10, 0, 0, 0);
        acc11 = __builtin_amdgcn_mfma_f32_16x16x32_f16(a1, b1, acc11, 0, 0, 0);
    }

    const floatx4* accs[4] = { &acc00, &acc01, &acc10, &acc11 };
#pragma unroll
    for (int r = 0; r < 2; ++r) {
#pragma unroll
        for (int c = 0; c < 2; ++c) {
            const floatx4 a = *accs[r * 2 + c];
            const int n = bn + wc + c * 16 + l15;
            const float bv = bias ? bias[n] : 0.f;
#pragma unroll
            for (int i = 0; i < 4; ++i) {
                const int m = bm + wr + r * 16 + quad * 4 + i;
                if (m < M) C[(size_t)m * Nout + n] = (_Float16)actf(a[i] + bv, act);
            }
        }
    }
}

// ---------------------------------------------------------------------------
// GAT xp GEMM with fused attention dots (kept from R13 -- it won).
// ---------------------------------------------------------------------------
__global__ __launch_bounds__(256) void gemm_dots_k(
    const _Float16* __restrict__ A, const _Float16* __restrict__ W,
    _Float16* __restrict__ C, const float* __restrict__ asrc,
    const float* __restrict__ adst, float* __restrict__ ssrc,
    float* __restrict__ sdst, int M)
{
    __shared__ unsigned short Als[64 * 136];
    __shared__ unsigned short Bls[64 * 136];
    const int tid = threadIdx.x;
    const int bm = blockIdx.y * 64;
    const int bn = blockIdx.x * 64;

    for (int i = tid; i < 1024; i += 256) {
        const int e8 = i << 3;
        const int r = e8 >> 7;
        const int c = e8 & 127;
        short8 av = {};
        if (bm + r < M) av = *(const short8*)(A + (size_t)(bm + r) * 128 + c);
        *(short8*)(Als + r * 136 + c) = av;
        *(short8*)(Bls + r * 136 + c) = *(const short8*)(W + (size_t)(bn + r) * 128 + c);
    }
    __syncthreads();

    const int wave = tid >> 6;
    const int lane = tid & 63;
    const int wr = (wave >> 1) * 32;
    const int wc = (wave & 1) * 32;
    const int l15 = lane & 15;
    const int quad = lane >> 4;

    floatx4 acc00 = {}, acc01 = {}, acc10 = {}, acc11 = {};
    for (int k0 = 0; k0 < 128; k0 += 32) {
        const half8v a0 = *(const half8v*)(Als + (wr + l15) * 136 + k0 + quad * 8);
        const half8v a1 = *(const half8v*)(Als + (wr + 16 + l15) * 136 + k0 + quad * 8);
        const half8v b0 = *(const half8v*)(Bls + (wc + l15) * 136 + k0 + quad * 8);
        const half8v b1 = *(const half8v*)(Bls + (wc + 16 + l15) * 136 + k0 + quad * 8);
        acc00 = __builtin_amdgcn_mfma_f32_16x16x32_f16(a0, b0, acc00, 0, 0, 0);
        acc01 = __builtin_amdgcn_mfma_f32_16x16x32_f16(a0, b1, acc01, 0, 0, 0);
        acc10 = __builtin_amdgcn_mfma_f32_16x16x32_f16(a1, b0, acc10, 0, 0, 0);
        acc11 = __builtin_amdgcn_mfma_f32_16x16x32_f16(a1, b1, acc11, 0, 0, 0);
    }

    // write C
    const floatx4* accs[4] = { &acc00, &acc01, &acc10, &acc11 };
#pragma unroll
    for (int r = 0; r < 2; ++r)
#pragma unroll
        for (int c = 0; c < 2; ++c) {
            const floatx4 a = *accs[r * 2 + c];
            const int n = bn + wc + c * 16 + l15;
#pragma unroll
            for (int i = 0; i < 4; ++i) {
                const int m = bm + wr + r * 16 + quad * 4 + i;
                if (m < M) C[(size_t)m * 128 + n] = (_Float16)a[i];
            }
        }

    // fused dots
    const int n0 = bn + wc + l15;
    const int n1 = n0 + 16;
    const float as0 = asrc[n0], as1 = asrc[n1];
    const float ad0 = adst[n0], ad1 = adst[n1];
#pragma unroll
    for (int r = 0; r < 2; ++r) {
        const floatx4 a0 = r ? acc10 : acc00;
        const floatx4 a1 = r ? acc11 : acc01;
#pragma unroll
        for (int i = 0; i < 4; ++i) {
            float vs = a0[i] * as0 + a1[i] * as1;
            float vd = a0[i] * ad0 + a1[i] * ad1;
            vs += __shfl_down(vs, 8, 16);
            vs += __shfl_down(vs, 4, 16);
            vs += __shfl_down(vs, 2, 16);
            vs += __shfl_down(vs, 1, 16);
            vd += __shfl_down(vd, 8, 16);
            vd += __shfl_down(vd, 4, 16);
            vd += __shfl_down(vd, 2, 16);
            vd += __shfl_down(vd, 1, 16);
            const int m = bm + wr + r * 16 + quad * 4 + i;
            if (l15 == 0 && m < M) {
                atomicAdd(ssrc + m, vs);
                atomicAdd(sdst + m, vd);
            }
        }
    }
}

// ---------------------------------------------------------------------------
// Fused lin1 + p GEMM (kept from R13 -- it won).
// ---------------------------------------------------------------------------
__global__ __launch_bounds__(256) void lin1p_k(
    const _Float16* __restrict__ xH, const _Float16* __restrict__ lin1_wH,
    const float* __restrict__ lin1_b, const _Float16* __restrict__ nd1wAH,
    _Float16* __restrict__ x1H, _Float16* __restrict__ pH, int M)
{
    __shared__ _Float16 sXin[64 * 72];
    __shared__ _Float16 sX1 [64 * 136];
    const int tid = threadIdx.x;
    const int bm = blockIdx.x * 64;

    for (int i = tid; i < 512; i += 256) {
        const int e8 = i << 3;
        const int r = e8 >> 6;
        const int c = e8 & 63;
        const int m = bm + r;
        half8v v = {};
        if (m < M) v = *(const half8v*)(xH + (size_t)m * 64 + c);
        *(half8v*)(sXin + r * 72 + c) = v;
    }
    __syncthreads();

    const int wave = tid >> 6, lane = tid & 63;
    const int l15 = lane & 15, quad = lane >> 4;
    const int wr = (wave >> 1) * 32;
    const int wc = (wave & 1) * 64;

    // stage 1: x1 = leaky(x @ lin1_w^T + b), K=64
    {
        floatx4 acc[2][4] = {};
#pragma unroll
        for (int k = 0; k < 2; ++k) {
            half8v a[2];
#pragma unroll
            for (int rf = 0; rf < 2; ++rf)
                a[rf] = *(const half8v*)(sXin + (wr + rf * 16 + l15) * 72 + k * 32 + quad * 8);
#pragma unroll
            for (int ct = 0; ct < 4; ++ct) {
                const half8v b = *(const half8v*)(lin1_wH + (size_t)(wc + ct * 16 + l15) * 64 + k * 32 + quad * 8);
#pragma unroll
                for (int rf = 0; rf < 2; ++rf)
                    acc[rf][ct] = __builtin_amdgcn_mfma_f32_16x16x32_f16(a[rf], b, acc[rf][ct], 0, 0, 0);
            }
        }
#pragma unroll
        for (int rf = 0; rf < 2; ++rf)
#pragma unroll
            for (int ct = 0; ct < 4; ++ct) {
                const int n = wc + ct * 16 + l15;
                const float bv = lin1_b[n];
#pragma unroll
                for (int i = 0; i < 4; ++i) {
                    const int rloc = wr + rf * 16 + quad * 4 + i;
                    float v = acc[rf][ct][i] + bv;
                    v = v >= 0.f ? v : 0.01f * v;
                    const _Float16 h = (_Float16)v;
                    sX1[rloc * 136 + n] = h;
                    const int m = bm + rloc;
                    if (m < M) x1H[(size_t)m * 128 + n] = h;
                }
            }
    }
    __syncthreads();

    // stage 2: p = x1 @ nd1wA^T, K=128
    {
        floatx4 acc[2][4] = {};
#pragma unroll
        for (int k = 0; k < 4; ++k) {
            half8v a[2];
#pragma unroll
            for (int rf = 0; rf < 2; ++rf)
                a[rf] = *(const half8v*)(sX1 + (wr + rf * 16 + l15) * 136 + k * 32 + quad * 8);
#pragma unroll
            for (int ct = 0; ct < 4; ++ct) {
                const half8v b = *(const half8v*)(nd1wAH + (size_t)(wc + ct * 16 + l15) * 128 + k * 32 + quad * 8);
#pragma unroll
                for (int rf = 0; rf < 2; ++rf)
                    acc[rf][ct] = __builtin_amdgcn_mfma_f32_16x16x32_f16(a[rf], b, acc[rf][ct], 0, 0, 0);
            }
        }
#pragma unroll
        for (int rf = 0; rf < 2; ++rf)
#pragma unroll
            for (int ct = 0; ct < 4; ++ct) {
                const int n = wc + ct * 16 + l15;
#pragma unroll
                for (int i = 0; i < 4; ++i) {
                    const int m = bm + wr + rf * 16 + quad * 4 + i;
                    if (m < M) pH[(size_t)m * 128 + n] = (_Float16)acc[rf][ct][i];
                }
            }
    }
}

// ---------------------------------------------------------------------------
// Fused GRU v6 (f16): block = 64 rows x 64 cols, grid.y=2 col-halves.
// ---------------------------------------------------------------------------
__global__ __launch_bounds__(256, 4) void gru_fused4_k(
    const _Float16* __restrict__ xin, const _Float16* __restrict__ hin,
    const _Float16* __restrict__ wih, const _Float16* __restrict__ whh,
    const float* __restrict__ bih, const float* __restrict__ bhh,
    _Float16* __restrict__ xout, int M)
{
    __shared__ unsigned short sX[64 * 136];
    __shared__ unsigned short sH[64 * 136];

    const int tid = threadIdx.x;
    const int bm = blockIdx.x * 64;

    for (int i = tid; i < 1024; i += 256) {
        const int e8 = i << 3;
        const int r = e8 >> 7;
        const int c = e8 & 127;
        const int m = bm + r;
        short8 xv = {}, hv = {};
        if (m < M) {
            xv = *(const short8*)(xin + (size_t)m * 128 + c);
            hv = *(const short8*)(hin + (size_t)m * 128 + c);
        }
        *(short8*)(sX + r * 136 + c) = xv;
        *(short8*)(sH + r * 136 + c) = hv;
    }
    __syncthreads();

    const int wave = tid >> 6;
    const int lane = tid & 63;
    const int l15 = lane & 15;
    const int quad = lane >> 4;
    const int j0 = (blockIdx.y * 4 + wave) * 16;
    const int j = j0 + l15;

    const float br  = bih[j] + bhh[j];
    const float bz  = bih[128 + j] + bhh[128 + j];
    const float bni = bih[256 + j];
    const float bnh = bhh[256 + j];

    floatx4 aR[4] = {}, aZ[4] = {}, aNi[4] = {}, aNh[4] = {};

#pragma unroll
    for (int k = 0; k < 4; ++k) {
        const size_t wrow = (size_t)(j0 + l15) * 128 + k * 32 + quad * 8;
        const half8v wri = *(const half8v*)(wih + wrow);
        const half8v wzi = *(const half8v*)(wih + 128 * 128 + wrow);
        const half8v wni = *(const half8v*)(wih + 2 * 128 * 128 + wrow);
        const half8v wrh = *(const half8v*)(whh + wrow);
        const half8v wzh = *(const half8v*)(whh + 128 * 128 + wrow);
        const half8v wnh = *(const half8v*)(whh + 2 * 128 * 128 + wrow);
#pragma unroll
        for (int rf = 0; rf < 4; ++rf) {
            const half8v ax = *(const half8v*)(sX + (rf * 16 + l15) * 136 + k * 32 + quad * 8);
            const half8v ah = *(const half8v*)(sH + (rf * 16 + l15) * 136 + k * 32 + quad * 8);
            aR[rf]  = __builtin_amdgcn_mfma_f32_16x16x32_f16(ax, wri, aR[rf], 0, 0, 0);
            aR[rf]  = __builtin_amdgcn_mfma_f32_16x16x32_f16(ah, wrh, aR[rf], 0, 0, 0);
            aZ[rf]  = __builtin_amdgcn_mfma_f32_16x16x32_f16(ax, wzi, aZ[rf], 0, 0, 0);
            aZ[rf]  = __builtin_amdgcn_mfma_f32_16x16x32_f16(ah, wzh, aZ[rf], 0, 0, 0);
            aNi[rf] = __builtin_amdgcn_mfma_f32_16x16x32_f16(ax, wni, aNi[rf], 0, 0, 0);
            aNh[rf] = __builtin_amdgcn_mfma_f32_16x16x32_f16(ah, wnh, aNh[rf], 0, 0, 0);
        }
    }

#pragma unroll
    for (int rf = 0; rf < 4; ++rf) {
#pragma unroll
        for (int i = 0; i < 4; ++i) {
            const int m = bm + rf * 16 + quad * 4 + i;
            if (m >= M) continue;
            const float rg = fsig(aR[rf][i] + br);
            const float zg = fsig(aZ[rf][i] + bz);
            const float ng = ftanh(aNi[rf][i] + bni + rg * (aNh[rf][i] + bnh));
            const float hp = (float)((const _Float16*)sH)[(rf * 16 + quad * 4 + i) * 136 + j];
            const float v = (1.f - zg) * ng + zg * hp;
            xout[(size_t)m * 128 + j] = (_Float16)(v > 0.f ? v : 0.f);
        }
    }
}

// ---------------------------------------------------------------------------
// CSR build: histogram + two-level scan + slot fill (stateless per launch).
// fill_csr also reorders edge_attr into CSR slot order (fp32 -> f16), so
// nd_gather reads ea sequentially (no random 32B rows, no csr_eid).
// ---------------------------------------------------------------------------
__global__ void hist_k(const int* __restrict__ ei, int* __restrict__ deg, int E)
{
    int e = blockIdx.x * 256 + threadIdx.x;
    if (e >= E) return;
    atomicAdd(deg + ei[E + e], 1);
}

__global__ __launch_bounds__(1024) void scan_part_k(const int* __restrict__ deg,
                                                    int* __restrict__ bsum, int n)
{
    __shared__ int sh[1024];
    const int t = threadIdx.x;
    const int i = blockIdx.x * 1024 + t;
    sh[t] = (i < n) ? deg[i] : 0;
    __syncthreads();
#pragma unroll
    for (int off = 512; off; off >>= 1) {
        if (t < off) sh[t] += sh[t + off];
        __syncthreads();
    }
    if (t == 0) bsum[blockIdx.x] = sh[0];
}

__global__ void scan_tops_k(const int* __restrict__ bsum, int* __restrict__ boff,
                            int nb, int* __restrict__ rowptr, int n)
{
    if (threadIdx.x != 0 || blockIdx.x != 0) return;
    int run = 0;
    for (int b = 0; b < nb; ++b) { boff[b] = run; run += bsum[b]; }
    rowptr[n] = run;
}

__global__ __launch_bounds__(1024) void scan_final_k(const int* __restrict__ deg,
                                                     const int* __restrict__ boff,
                                                     int* __restrict__ rowptr, int n)
{
    __shared__ int sh[1024];
    const int t = threadIdx.x;
    const int i = blockIdx.x * 1024 + t;
    const int v = (i < n) ? deg[i] : 0;
    sh[t] = v;
    __syncthreads();
#pragma unroll
    for (int off = 1; off < 1024; off <<= 1) {
        int add = (t >= off) ? sh[t - off] : 0;
        __syncthreads();
        sh[t] += add;
        __syncthreads();
    }
    if (i < n) rowptr[i] = boff[blockIdx.x] + sh[t] - v;   // exclusive
}

__global__ void fill_csr_k(const int* __restrict__ ei, const float* __restrict__ ea,
                           const int* __restrict__ rowptr, int* __restrict__ cursor,
                           int* __restrict__ csr_src, _Float16* __restrict__ eaP, int E)
{
    int e = blockIdx.x * 256 + threadIdx.x;
    if (e >= E) return;
    int s = ei[e], d = ei[E + e];
    int pos = atomicAdd(cursor + d, 1);
    int slot = rowptr[d] + pos;
    csr_src[slot] = s;
    const float4 a0 = *(const float4*)(ea + (size_t)e * 16);
    const float4 a1 = *(const float4*)(ea + (size_t)e * 16 + 4);
    const float4 a2 = *(const float4*)(ea + (size_t)e * 16 + 8);
    const float4 a3 = *(const float4*)(ea + (size_t)e * 16 + 12);
    half8v h0, h1;
    h0[0] = (_Float16)a0.x; h0[1] = (_Float16)a0.y; h0[2] = (_Float16)a0.z; h0[3] = (_Float16)a0.w;
    h0[4] = (_Float16)a1.x; h0[5] = (_Float16)a1.y; h0[6] = (_Float16)a1.z; h0[7] = (_Float16)a1.w;
    h1[0] = (_Float16)a2.x; h1[1] = (_Float16)a2.y; h1[2] = (_Float16)a2.z; h1[3] = (_Float16)a2.w;
    h1[4] = (_Float16)a3.x; h1[5] = (_Float16)a3.y; h1[6] = (_Float16)a3.z; h1[7] = (_Float16)a3.w;
    *(half8v*)(eaP + (size_t)slot * 16) = h0;
    *(half8v*)(eaP + (size_t)slot * 16 + 8) = h1;
}

// batch is sorted: fill gptr[g] = first node of graph g (gptr[G] = N)
__global__ void gptr_k(const int* __restrict__ batch, int* __restrict__ gptr,
                       int N, int G)
{
    int n = blockIdx.x * 256 + threadIdx.x;
    if (n >= N) return;
    if (n == 0) {
        for (int g = 0; g <= batch[0]; ++g) gptr[g] = 0;
    } else {
        const int a = batch[n - 1], b = batch[n];
        for (int g = a + 1; g <= b; ++g) gptr[g] = n;
    }
    if (n == N - 1) {
        for (int g = batch[N - 1] + 1; g <= G; ++g) gptr[g] = N;
    }
}

// per-graph contiguous sum (no atomics, G-wide parallel): aggH f16
__global__ __launch_bounds__(128) void graph_sum_k(
    const _Float16* __restrict__ xc, const int* __restrict__ gptr,
    _Float16* __restrict__ aggH)
{
    const int g = blockIdx.x;
    const int t = threadIdx.x;   // feature
    const int n0 = gptr[g], n1 = gptr[g + 1];
    float acc = 0.f;
    for (int n = n0; n < n1; ++n) acc += (float)xc[(size_t)n * 128 + t];
    aggH[(size_t)g * 128 + t] = (_Float16)acc;
}

// ---------------------------------------------------------------------------
// Multi-segment fp32 -> f16 conversion (one dispatch for all flat tensors)
// ---------------------------------------------------------------------------
struct CvtSeg { const float* src; _Float16* dst; int n; };
struct CvtArgs { CvtSeg s[12]; int count; };

__global__ void cvt_multi_k(CvtArgs a)
{
    const int seg = blockIdx.y;
    if (seg >= a.count) return;
    const CvtSeg cs = a.s[seg];
    for (int i = blockIdx.x * 256 + threadIdx.x; i < cs.n; i += gridDim.x * 256)
        cs.dst[i] = (_Float16)cs.src[i];
}

// nd_lin1_w[:,0:128] (pitch 144) -> packed f16 [128][128]
__global__ void cvt_ndwA_k(const float* __restrict__ ndw, _Float16* __restrict__ outp)
{
    int t = blockIdx.x * 256 + threadIdx.x;
    if (t >= 16384) return;
    int r = t >> 7, c = t & 127;
    outp[r * 128 + c] = (_Float16)ndw[r * 144 + c];
}

// nd_lin1_w[:,128:144] (pitch 144) -> f16 table [128][16]
__global__ void cvt_ndwB_k(const float* __restrict__ ndw, _Float16* __restrict__ outp)
{
    int t = blockIdx.x * 256 + threadIdx.x;
    if (t >= 2048) return;
    int r = t >> 4, k = t & 15;
    outp[r * 16 + k] = (_Float16)ndw[r * 144 + 128 + k];
}

// ---------------------------------------------------------------------------
// nd_conv gather v5: R12 structure (1 feature/thread, serial edges with
// prefetch) + sequential eaP (CSR slot order) + p-value prefetch.
// ---------------------------------------------------------------------------
__global__ __launch_bounds__(128) void nd_gather_k(
    const int* __restrict__ rowptr, const int* __restrict__ csr_src,
    const _Float16* __restrict__ eaP, const _Float16* __restrict__ wH,
    const _Float16* __restrict__ pH, _Float16* __restrict__ outp)
{
    const int d = blockIdx.x;
    const int t = threadIdx.x;   // feature 0..127
    const half8v w0 = *(const half8v*)(wH + t * 16);
    const half8v w1 = *(const half8v*)(wH + t * 16 + 8);

    const int b0 = rowptr[d], b1 = rowptr[d + 1];
    float acc = 0.f;
    float pv = 0.f;
    if (b0 < b1) pv = (float)pH[(size_t)csr_src[b0] * 128 + t];
    for (int i = b0; i < b1; ++i) {
        float npv = 0.f;
        if (i + 1 < b1) npv = (float)pH[(size_t)csr_src[i + 1] * 128 + t];
        const half8v e0 = *(const half8v*)(eaP + (size_t)i * 16);
        const half8v e1 = *(const half8v*)(eaP + (size_t)i * 16 + 8);
        float q = 0.f;
        q = hdot2(H2(e0, 0), H2(w0, 0), q);
        q = hdot2(H2(e0, 1), H2(w0, 1), q);
        q = hdot2(H2(e0, 2), H2(w0, 2), q);
        q = hdot2(H2(e0, 3), H2(w0, 3), q);
        q = hdot2(H2(e1, 0), H2(w1, 0), q);
        q = hdot2(H2(e1, 1), H2(w1, 1), q);
        q = hdot2(H2(e1, 2), H2(w1, 2), q);
        q = hdot2(H2(e1, 3), H2(w1, 3), q);
        const float v = pv + q;
        acc += v >= 0.f ? v : 0.01f * v;
        pv = npv;
    }
    outp[(size_t)d * 128 + t] = (_Float16)acc;
}

// ---------------------------------------------------------------------------
// Fused GAT aggregation -- one pass (softmax shift-invariance, |a| small)
// ---------------------------------------------------------------------------
__global__ __launch_bounds__(128) void gat_gather_k(
    const int* __restrict__ rowptr, const int* __restrict__ csr_src,
    const float* __restrict__ ssrc, const float* __restrict__ sdst,
    const _Float16* __restrict__ xp, const float* __restrict__ bias,
    _Float16* __restrict__ outp)
{
    const int d = blockIdx.x;
    const int t = threadIdx.x;
    __shared__ float red[128];
    __shared__ float lw[128];
    __shared__ int   ls[128];
    __shared__ float racc[4][128];

    const int b0 = rowptr[d], b1 = rowptr[d + 1];
    const int deg = b1 - b0;
    const float sdd = sdst[d];

    const int g  = t >> 5;       // edge group 0..3
    const int fq = t & 31;       // feature quad
    float4 acc = make_float4(0.f, 0.f, 0.f, 0.f);
    float dpart = 0.f;
    for (int base = b0; base < b1; base += 128) {
        const int len = min(128, b1 - base);
        if (t < len) {
            const int s = csr_src[base + t];
            float a = ssrc[s] + sdd;
            a = a >= 0.f ? a : 0.01f * a;
            const float w = __expf(a);     // |a| small -> safe
            lw[t] = w;
            ls[t] = s;
            dpart += w;
        }
        __syncthreads();
        for (int j = 0; j < len; j += 4) {
            const int jj = j + g;
            if (jj < len) {
                const float w = lw[jj];
                const half4v hv = *(const half4v*)(xp + (size_t)ls[jj] * 128 + fq * 4);
                acc.x += w * (float)hv[0];
                acc.y += w * (float)hv[1];
                acc.z += w * (float)hv[2];
                acc.w += w * (float)hv[3];
            }
        }
        __syncthreads();
    }

    red[t] = dpart;
    __syncthreads();
#pragma unroll
    for (int off = 64; off; off >>= 1) {
        if (t < off) red[t] += red[t + off];
        __syncthreads();
    }
    const float denom = red[0];

    racc[g][fq * 4 + 0] = acc.x;
    racc[g][fq * 4 + 1] = acc.y;
    racc[g][fq * 4 + 2] = acc.z;
    racc[g][fq * 4 + 3] = acc.w;
    __syncthreads();

    const float s4 = racc[0][t] + racc[1][t] + racc[2][t] + racc[3][t];
    float v = (deg > 0 ? s4 / denom : 0.f) + bias[t];
    outp[(size_t)d * 128 + t] = (_Float16)(v > 0.f ? v : __expf(v) - 1.f);   // elu
}

// ---------------------------------------------------------------------------
// Fused GIN+LSTM readout: 16 graphs/block (125 blocks, 25.6 KB LDS).
// ---------------------------------------------------------------------------
__global__ __launch_bounds__(256) void gin_lstm_k(
    const _Float16* __restrict__ aggH,
    const _Float16* __restrict__ ginw, const float* __restrict__ ginb,
    const _Float16* __restrict__ lwih, const _Float16* __restrict__ lwhh,
    const float* __restrict__ lbih, const float* __restrict__ lbhh,
    const float* __restrict__ l2w, const float* __restrict__ l2b,
    float* __restrict__ y, int G)
{
    __shared__ _Float16 sOa[16 * 136];
    __shared__ _Float16 sOb[16 * 136];
    __shared__ _Float16 sG [16 * 136];
    __shared__ _Float16 sT [16 * 136];   // hg (f16, GEMM operand)
    __shared__ float    sC [16 * 128];   // hg (fp32, cell state)

    const int tid = threadIdx.x, wave = tid >> 6, lane = tid & 63;
    const int l15 = lane & 15, quad = lane >> 4;
    const int g0 = blockIdx.x * 16;

    {
        const int r = tid >> 4;           // 0..15
        const int c = (tid & 15) * 8;
        half8v v = {};
        if (g0 + r < G) v = *(const half8v*)(aggH + (size_t)(g0 + r) * 128 + c);
        *(half8v*)(sG + r * 136 + c) = v;
        half8v rv;
#pragma unroll
        for (int i = 0; i < 8; ++i) rv[i] = (float)v[i] > 0.f ? v[i] : (_Float16)0.f;
        *(half8v*)(sOa + r * 136 + c) = rv;
    }
    __syncthreads();

    _Float16* sIn = sOa;
    _Float16* sOut = sOb;
#pragma unroll
    for (int ts = 0; ts < 2; ++ts) {
        for (int ci = 0; ci < 2; ++ci) {
            const int j0 = (wave * 2 + ci) * 16;
            floatx4 acc = {};
#pragma unroll
            for (int k = 0; k < 4; ++k) {
                const half8v b = *(const half8v*)(ginw + (size_t)(j0 + l15) * 128 + k * 32 + quad * 8);
                const half8v a = *(const half8v*)(sIn + l15 * 136 + k * 32 + quad * 8)
                               + *(const half8v*)(sG  + l15 * 136 + k * 32 + quad * 8);
                acc = __builtin_amdgcn_mfma_f32_16x16x32_f16(a, b, acc, 0, 0, 0);
            }
            const int j = j0 + l15;
            const float bg = ginb[j];
#pragma unroll
            for (int i = 0; i < 4; ++i) {
                const int row = quad * 4 + i;
                float v = acc[i] + bg;
                v = v > 0.f ? v : __expf(v) - 1.f;
                sT[row * 136 + j] = (_Float16)v;
                sC[row * 128 + j] = v;
            }
        }
        __syncthreads();

        for (int ci = 0; ci < 2; ++ci) {
            const int j0 = (wave * 2 + ci) * 16;
            floatx4 acc[4] = {};
#pragma unroll
            for (int k = 0; k < 4; ++k) {
                const half8v ao = *(const half8v*)(sIn + l15 * 136 + k * 32 + quad * 8);
                const half8v ah = *(const half8v*)(sT  + l15 * 136 + k * 32 + quad * 8);
#pragma unroll
                for (int gt = 0; gt < 4; ++gt) {
                    const half8v bw = *(const half8v*)(lwih + (size_t)(gt * 128 + j0 + l15) * 128 + k * 32 + quad * 8);
                    const half8v bh = *(const half8v*)(lwhh + (size_t)(gt * 128 + j0 + l15) * 128 + k * 32 + quad * 8);
                    acc[gt] = __builtin_amdgcn_mfma_f32_16x16x32_f16(ao, bw, acc[gt], 0, 0, 0);
                    acc[gt] = __builtin_amdgcn_mfma_f32_16x16x32_f16(ah, bh, acc[gt], 0, 0, 0);
                }
            }
            const int j = j0 + l15;
            const float bi_ = lbih[j]       + lbhh[j];
            const float bf_ = lbih[128 + j] + lbhh[128 + j];
            const float bgg = lbih[256 + j] + lbhh[256 + j];
            const float bo_ = lbih[384 + j] + lbhh[384 + j];
#pragma unroll
            for (int i = 0; i < 4; ++i) {
                const int row = quad * 4 + i;
                const float hg = sC[row * 128 + j];
                const float c2 = fsig(acc[1][i] + bf_) * hg
                               + fsig(acc[0][i] + bi_) * ftanh(acc[2][i] + bgg);
                const float on = fsig(acc[3][i] + bo_) * ftanh(c2);
                sOut[row * 136 + j] = (_Float16)on;
            }
        }
        __syncthreads();
        _Float16* tmp = sIn; sIn = sOut; sOut = tmp;
    }

    if (tid < 64) {
        const int r = tid >> 2;      // 0..15
        const int part = tid & 3;
        float v = 0.f;
        for (int j = part * 32; j < part * 32 + 32; ++j)
            v += (float)sIn[r * 136 + j] * l2w[j];
        v += __shfl_down(v, 2);
        v += __shfl_down(v, 1);
        if (part == 0 && g0 + r < G) y[g0 + r] = v + l2b[0];
    }
}

// ---------------------------------------------------------------------------

extern "C" void kernel_launch(void* const* d_in, const int* in_sizes, int n_in,
                              void* d_out, int out_size, void* d_ws, size_t ws_size,
                              hipStream_t stream)
{
    const float* x      = (const float*)d_in[0];
    const int*   ei     = (const int*)  d_in[1];
    const float* ea     = (const float*)d_in[2];
    const int*   batch  = (const int*)  d_in[3];
    const float* lin1_w = (const float*)d_in[4];
    const float* lin1_b = (const float*)d_in[5];
    const float* nd1w   = (const float*)d_in[6];
    const float* nd2w   = (const float*)d_in[7];
    const float* ndb    = (const float*)d_in[8];
    const float* g0wih  = (const float*)d_in[9];
    const float* g0whh  = (const float*)d_in[10];
    const float* g0bih  = (const float*)d_in[11];
    const float* g0bhh  = (const float*)d_in[12];
    const float* gatw   = (const float*)d_in[13];
    const float* gatas  = (const float*)d_in[14];
    const float* gatad  = (const float*)d_in[15];
    const float* gatb   = (const float*)d_in[16];
    const float* gwih   = (const float*)d_in[17];
    const float* gwhh   = (const float*)d_in[18];
    const float* gbih   = (const float*)d_in[19];
    const float* gbhh   = (const float*)d_in[20];
    const float* ginw   = (const float*)d_in[21];
    const float* ginb   = (const float*)d_in[22];
    const float* lwih   = (const float*)d_in[23];
    const float* lwhh   = (const float*)d_in[24];
    const float* lbih   = (const float*)d_in[25];
    const float* lbhh   = (const float*)d_in[26];
    const float* l2w    = (const float*)d_in[27];
    const float* l2b    = (const float*)d_in[28];
    float* outp = (float*)d_out;

    const int N = NN, E = EE, G = GG;
    const int Npad = (N + 63) & ~63;

    float* ws = (float*)d_ws;
    size_t off = 0;
    auto alloc = [&](size_t n) {
        float* r = ws + off;
        off += (n + 63) & ~(size_t)63;
        return r;
    };
    // f16 node pipeline (sizes in floats = halves/2)
    _Float16* xH    = (_Float16*)alloc((size_t)N * 32);   // N*64
    _Float16* x1H   = (_Float16*)alloc((size_t)N * 64);   // N*128 (ping)
    _Float16* hbufH = (_Float16*)alloc((size_t)N * 64);
    _Float16* accbH = (_Float16*)alloc((size_t)N * 64);
    _Float16* xcH   = (_Float16*)alloc((size_t)N * 64);   // (pong)
    _Float16* pH    = (_Float16*)alloc((size_t)N * 64);
    _Float16* eaP   = (_Float16*)alloc((size_t)E * 8);    // E*16, CSR slot order
    _Float16* aggH  = (_Float16*)alloc((size_t)G * 64);   // G*128
    // f16 weights
    _Float16* lin1_wH = (_Float16*)alloc(4096);           // 128x64
    _Float16* nd1wAH  = (_Float16*)alloc(8192);           // 128x128
    _Float16* ndwBH   = (_Float16*)alloc(1024);           // 128x16
    _Float16* nd2wH   = (_Float16*)alloc(8192);
    _Float16* g0wihH  = (_Float16*)alloc(24576);
    _Float16* g0whhH  = (_Float16*)alloc(24576);
    _Float16* gwihH   = (_Float16*)alloc(49152);          // 2 layers
    _Float16* gwhhH   = (_Float16*)alloc(49152);
    _Float16* gatwH   = (_Float16*)alloc(16384);          // 2 layers
    _Float16* ginwH   = (_Float16*)alloc(8192);           // 128x128
    _Float16* lwihH   = (_Float16*)alloc(32768);          // 512x128
    _Float16* lwhhH   = (_Float16*)alloc(32768);
    // fp32 dot buffers (2 GAT layers, contiguous for single memset)
    float* ssrcA = alloc((size_t)N);
    float* sdstA = alloc((size_t)N);
    float* ssrcB = alloc((size_t)N);
    float* sdstB = alloc((size_t)N);
    // CSR + graph ptr
    int* deg     = (int*)alloc((size_t)N);
    int* rowptr  = (int*)alloc((size_t)N + 1);
    int* cursor  = (int*)alloc((size_t)N);
    int* bsum    = (int*)alloc(64);
    int* boff    = (int*)alloc(64);
    int* csr_src = (int*)alloc((size_t)E);
    int* gptr    = (int*)alloc((size_t)G + 1);
    (void)ws_size;

    auto gemmh = [&](const _Float16* A, const _Float16* W, const float* bias,
                     _Float16* C, int M, int K, int Nout, int act) {
        dim3 grid(Nout / 64, (M + 63) / 64);
        gemm_f16_k<<<grid, 256, 0, stream>>>(A, W, bias, C, M, K, Nout, act);
    };
    auto nb = [](int n) { return (n + 255) / 256; };

    auto gru = [&](const _Float16* xin, const _Float16* hin,
                   const _Float16* wih, const _Float16* whh,
                   const float* bih, const float* bhh, _Float16* xout) {
        dim3 grid((N + 63) / 64, 2);
        gru_fused4_k<<<grid, 256, 0, stream>>>(
            xin, hin, wih, whh, bih, bhh, xout, N);
    };

    // 0) CSR build (with ea reorder) + gptr + dot-buffer zero + f16 conversions
    hipMemsetAsync(deg, 0, (size_t)N * 4, stream);
    hipMemsetAsync(cursor, 0, (size_t)N * 4, stream);
    hipMemsetAsync(ssrcA, 0, (size_t)Npad * 4 * 4, stream);   // ssrcA..sdstB
    hist_k<<<nb(E), 256, 0, stream>>>(ei, deg, E);
    const int nblk = (N + 1023) / 1024;   // 49
    scan_part_k<<<nblk, 1024, 0, stream>>>(deg, bsum, N);
    scan_tops_k<<<1, 64, 0, stream>>>(bsum, boff, nblk, rowptr, N);
    scan_final_k<<<nblk, 1024, 0, stream>>>(deg, boff, rowptr, N);
    fill_csr_k<<<nb(E), 256, 0, stream>>>(ei, ea, rowptr, cursor, csr_src, eaP, E);
    gptr_k<<<nb(N), 256, 0, stream>>>(batch, gptr, N, G);

    CvtArgs ca;
    ca.s[0]  = { x,      xH,      N * 64 };
    ca.s[1]  = { lin1_w, lin1_wH, 8192 };
    ca.s[2]  = { nd2w,   nd2wH,   16384 };
    ca.s[3]  = { g0wih,  g0wihH,  49152 };
    ca.s[4]  = { g0whh,  g0whhH,  49152 };
    ca.s[5]  = { gwih,   gwihH,   98304 };
    ca.s[6]  = { gwhh,   gwhhH,   98304 };
    ca.s[7]  = { gatw,   gatwH,   32768 };
    ca.s[8]  = { ginw,   ginwH,   16384 };
    ca.s[9]  = { lwih,   lwihH,   65536 };
    ca.s[10] = { lwhh,   lwhhH,   65536 };
    ca.count = 11;
    cvt_multi_k<<<dim3(2048, 11), 256, 0, stream>>>(ca);
    cvt_ndwA_k<<<64, 256, 0, stream>>>(nd1w, nd1wAH);
    cvt_ndwB_k<<<8, 256, 0, stream>>>(nd1w, ndwBH);

    // 1+2a) fused: x1 = leaky(x @ lin1^T + b); p = x1 @ W1a^T
    lin1p_k<<<(N + 63) / 64, 256, 0, stream>>>(
        xH, lin1_wH, lin1_b, nd1wAH, x1H, pH, N);

    // 2b) nd gather (sequential ea) + h GEMM
    nd_gather_k<<<N, 128, 0, stream>>>(rowptr, csr_src, eaP, ndwBH, pH, accbH);
    gemmh(accbH, nd2wH, ndb, hbufH, N, 128, 128, 2);

    // 3) xcur = relu(gru_cell(h, x1))
    gru(hbufH, x1H, g0wihH, g0whhH, g0bih, g0bhh, xcH);

    // 4) GAT layers (xp GEMM with fused attention dots)
    const _Float16* xcur = xcH;
    _Float16* xnext = x1H;
    for (int l = 0; l < 2; ++l) {
        float* ss = l ? ssrcB : ssrcA;
        float* sd = l ? sdstB : sdstA;
        dim3 grid(2, (N + 63) / 64);
        gemm_dots_k<<<grid, 256, 0, stream>>>(
            xcur, gatwH + (size_t)l * 16384, pH,
            gatas + l * 128, gatad + l * 128, ss, sd, N);
        gat_gather_k<<<N, 128, 0, stream>>>(rowptr, csr_src, ss, sd, pH,
                                            gatb + l * 128, hbufH);
        gru(hbufH, xcur, gwihH + (size_t)l * 49152, gwhhH + (size_t)l * 49152,
            gbih + l * 384, gbhh + l * 384, xnext);
        const _Float16* t = xcur; xcur = xnext; xnext = (_Float16*)t;
    }

    // 5) segment-sum (G-wide parallel)
    graph_sum_k<<<G, 128, 0, stream>>>(xcur, gptr, aggH);

    // 6-7) fused GIN+LSTM+final (16 graphs/block, 125 blocks)
    gin_lstm_k<<<(G + 15) / 16, 256, 0, stream>>>(
        aggH, ginwH, ginb, lwihH, lwhhH, lbih, lbhh, l2w, l2b, outp, G);
}